// Round 8
// baseline (83.192 us; speedup 1.0000x reference)
//
#include <hip/hip_runtime.h>

#define N 512
#define TOPK 153
#define KP 160
#define D 64
#define NB 32          // batches
#define BN (NB*N)
#define EPSF 1e-8f

// ---------------- ws layout (bytes) ----------------
// 0x100000: G     u64[N*8]       (32KB)  gated selection bitmask (target-major)
// 0x108000: GT    u64[N*8]       (32KB)  transpose bitmask (built via atomicOr)
// 0x110000: idxl  i32[N*KP]      (320KB) top-k source ids per target (rank order)
// 0x160000: wgtl  f32[N*KP]      (320KB) c^2 * rs_i  (row-scaled structural coeff)
// 0x1B0000: rs    f32[N]         1/sqrt(sum_k c_ik^2)   [max_common cancels]
// 0x1C0000: h     f32[BN*D]      (4MB, ends 0x5C0000)
// 0x5C0000: keysg u64[N*N]       (2MB)   per-row sortable keys (global, L1-broadcast)

union SMem {
    struct {                     // front blocks (~4.3KB)
        float cr[N];
        float q2[N];
        float ri[D];
    } f;
    struct { float xs[16*64]; } g;   // GEMM blocks (4KB; W read from L1)
};

// blocks 0..511: cosine row + exact top-k for node i.
//   Rank scan reads u64 keys from GLOBAL scratch via uniform (wave-broadcast)
//   loads -- single 16B L1 transaction on the VMEM pipe, NOT the per-CU LDS
//   pipe that serialized R7's ds_read_b128 scan (~25k cy/CU).
// blocks 512..1535: h = x @ W rides the same dispatch; W rows from L1 (16KB
//   resident), only xs staged in LDS.
__global__ __launch_bounds__(256)
void k_front4(const float* __restrict__ emb, const float* __restrict__ x,
              const float* __restrict__ W, float* __restrict__ h,
              int* __restrict__ idxl, unsigned long long* __restrict__ G,
              unsigned long long* __restrict__ GT,
              unsigned long long* __restrict__ keysg) {
    __shared__ SMem sm;
    int t = threadIdx.x;
    if (blockIdx.x >= 512) {                    // ---- h = x @ W ----
        int r0 = ((int)blockIdx.x - 512) * 16;
        ((float4*)sm.g.xs)[t] = ((const float4*)(x + r0*64))[t];
        __syncthreads();
        int row = t >> 4, f0 = (t & 15)*4;
        float ax=0, ay=0, az=0, aw=0;
        #pragma unroll 8
        for (int c = 0; c < 64; ++c) {
            float xv = sm.g.xs[row*64+c];                       // LDS broadcast
            float4 wv = *(const float4*)&W[c*64+f0];            // L1-hot global
            ax = fmaf(xv,wv.x,ax); ay = fmaf(xv,wv.y,ay);
            az = fmaf(xv,wv.z,az); aw = fmaf(xv,wv.w,aw);
        }
        float4 o; o.x=ax; o.y=ay; o.z=az; o.w=aw;
        ((float4*)(h + r0*64))[t] = o;
        return;
    }
    // ---- front: cosine row + top-k for node i ----
    int i = blockIdx.x;
    if (t < 16) ((float4*)sm.f.ri)[t] = ((const float4*)(emb + i*D))[t];
    __syncthreads();
    for (int j = t; j < N; j += 256) {          // dot(i,j), |j|^2 in one pass
        const float4* rj = (const float4*)(emb + j*D);
        float dot = 0.f, nsq = 0.f;
        #pragma unroll
        for (int q = 0; q < 16; ++q) {
            float4 v = rj[q];
            float4 u = ((const float4*)sm.f.ri)[q];             // LDS broadcast
            dot = fmaf(u.x,v.x,fmaf(u.y,v.y,fmaf(u.z,v.z,fmaf(u.w,v.w,dot))));
            nsq = fmaf(v.x,v.x,fmaf(v.y,v.y,fmaf(v.z,v.z,fmaf(v.w,v.w,nsq))));
        }
        sm.f.cr[j] = dot; sm.f.q2[j] = nsq;
    }
    __syncthreads();
    // cosine + sortable key build: monotonic float->u32, index in low 9 bits;
    // keys written to per-block GLOBAL scratch (coalesced), scanned via L1.
    float ni = sqrtf(sm.f.q2[i]);
    unsigned long long* kgr = keysg + (size_t)i * N;
    for (int j = t; j < N; j += 256) {
        float c = sm.f.cr[j] / (ni*sqrtf(sm.f.q2[j]) + EPSF);
        unsigned u = __float_as_uint(c);
        unsigned s = (u >> 31) ? ~u : (u | 0x80000000u);
        kgr[j] = ((unsigned long long)s << 9) | (unsigned)(511 - j);
    }
    __threadfence_block();
    __syncthreads();                             // drains vmcnt; keys visible
    // exact rank via key count: rank_j = #{m : key_m > key_j}
    unsigned long long k0 = kgr[t], k1 = kgr[t+256];    // coalesced own-key reads
    int r0 = 0, r1 = 0;
    const ulonglong2* k2 = (const ulonglong2*)kgr;
    #pragma unroll 8
    for (int m2 = 0; m2 < 256; ++m2) {
        ulonglong2 km = k2[m2];                  // uniform addr: 1 L1 transaction
        r0 += (km.x > k0); r0 += (km.y > k0);
        r1 += (km.x > k1); r1 += (km.y > k1);
    }
    bool s0 = r0 < TOPK, s1 = r1 < TOPK;
    if (s0) {
        idxl[i*KP + r0] = t;                     // rank order == ref order
        atomicOr(&GT[t*8 + (i>>6)], 1ull << (i&63));
    }
    if (s1) {
        idxl[i*KP + r1] = t + 256;
        atomicOr(&GT[(t+256)*8 + (i>>6)], 1ull << (i&63));
    }
    // G row via ballot: wave w owns candidate words w (t) and w+4 (t+256)
    unsigned long long b0 = __ballot(s0);
    unsigned long long b1 = __ballot(s1);
    int lane = t & 63, w = t >> 6;
    if (lane == 0) {
        G[i*8 + w]     = b0;
        G[i*8 + 4 + w] = b1;
    }
}

// Per-edge popcount weights; nb rows built on the fly as G|GT|self
// (all L1/L2-resident, 32KB each). Stores c^2*rs_i; rs_i = 1/sqrt(sum c^2).
__global__ __launch_bounds__(256)
void k_edge2(const unsigned long long* __restrict__ G,
             const unsigned long long* __restrict__ GT,
             const int* __restrict__ idxl,
             float* __restrict__ wgtl, float* __restrict__ rs) {
    __shared__ unsigned long long ni[8];
    __shared__ float red[4];
    __shared__ float rsb;
    int i = blockIdx.x, k = threadIdx.x;
    if (k < 8) {
        unsigned long long v = G[i*8+k] | GT[i*8+k];
        if ((i>>6) == k) v |= 1ull << (i&63);    // self loop
        ni[k] = v;
    }
    __syncthreads();
    float c2 = 0.f;
    if (k < TOPK) {
        int j = idxl[i*KP+k];
        int jw = j >> 6; unsigned long long jb = 1ull << (j&63);
        int c = 0;
        #pragma unroll
        for (int w = 0; w < 8; ++w) {
            unsigned long long nj = G[j*8+w] | GT[j*8+w];
            if (w == jw) nj |= jb;               // self loop (compile-time w)
            c += __popcll(ni[w] & nj);
        }
        c2 = (float)(c*c);                       // edge always has c>=2
    }
    float s = c2;
    #pragma unroll
    for (int o = 32; o > 0; o >>= 1) s += __shfl_down(s, o, 64);
    if ((k & 63) == 0) red[k>>6] = s;
    __syncthreads();
    if (k == 0) {
        float deg = red[0]+red[1]+red[2]+red[3]; // > 0 always
        float r = (float)(1.0/sqrt((double)deg));
        rsb = r; rs[i] = r;
    }
    __syncthreads();
    if (k < TOPK) wgtl[i*KP+k] = c2 * rsb;
}

// h[b] staged in LDS (conflict-free b128 gather); indices/weights read from
// global (wave-broadcast, L2-hot); final weight = wn[k] * rs[j] on the fly.
__global__ __launch_bounds__(512)
void k_agg3(const float* __restrict__ h, const int* __restrict__ idxl,
            const float* __restrict__ wn, const float* __restrict__ rs,
            const float* __restrict__ bias, float* __restrict__ out) {
    __shared__ float4 hs4[512*16];   // 128KB: h[b] staged
    int chunk = blockIdx.x, b = blockIdx.y, t = threadIdx.x;
    const float4* hb = (const float4*)h + b*8192;
    for (int e = t; e < 8192; e += 512) hs4[e] = hb[e];
    int lane = t & 63, wv = t >> 6;
    int ts = lane >> 4, fq = lane & 15;
    int tl = wv*4 + ts;              // local target 0..31
    float4 bv = ((const float4*)bias)[fq];
    __syncthreads();
    #pragma unroll
    for (int grp = 0; grp < 2; ++grp) {
        int ti = chunk*64 + grp*32 + tl;
        const int*   ip = &idxl[ti*KP];
        const float* wp = &wn[ti*KP];
        float ax=0, ay=0, az=0, aw=0;
        #pragma unroll 4
        for (int kk = 0; kk < TOPK; ++kk) {
            int j = ip[kk];
            float w = wp[kk] * rs[j];
            float4 hv = hs4[j*16 + fq];
            ax = fmaf(w,hv.x,ax); ay = fmaf(w,hv.y,ay);
            az = fmaf(w,hv.z,az); aw = fmaf(w,hv.w,aw);
        }
        float4 o; o.x = ax+bv.x; o.y = ay+bv.y; o.z = az+bv.z; o.w = aw+bv.w;
        ((float4*)out)[(b*512 + ti)*16 + fq] = o;
    }
}

extern "C" void kernel_launch(void* const* d_in, const int* in_sizes, int n_in,
                              void* d_out, int out_size, void* d_ws, size_t ws_size,
                              hipStream_t stream) {
    const float* x    = (const float*)d_in[0];   // [32,512,64]
    const float* W    = (const float*)d_in[1];   // [64,64]
    const float* bias = (const float*)d_in[2];   // [64]
    const float* emb  = (const float*)d_in[3];   // [512,64]
    float* out = (float*)d_out;

    char* ws = (char*)d_ws;
    unsigned long long* G     = (unsigned long long*)(ws + 0x100000);
    unsigned long long* GT    = (unsigned long long*)(ws + 0x108000);
    int*   idxl = (int*)(ws + 0x110000);
    float* wgtl = (float*)(ws + 0x160000);
    float* rs   = (float*)(ws + 0x1B0000);
    float* h    = (float*)(ws + 0x1C0000);
    unsigned long long* keysg = (unsigned long long*)(ws + 0x5C0000);

    hipMemsetAsync(GT, 0, N*8*sizeof(unsigned long long), stream);
    k_front4<<<512 + BN/16, 256, 0, stream>>>(emb, x, W, h, idxl, G, GT, keysg);
    k_edge2<<<N, 256, 0, stream>>>(G, GT, idxl, wgtl, rs);
    k_agg3<<<dim3(8, NB), 512, 0, stream>>>(h, idxl, wgtl, rs, bias, out);
}

// Round 9
// 72.912 us; speedup vs baseline: 1.1410x; 1.1410x over previous
//
#include <hip/hip_runtime.h>

#define N 512
#define TOPK 153
#define KP 160
#define D 64
#define NB 32          // batches
#define BN (NB*N)
#define EPSF 1e-8f

// ---------------- ws layout (bytes) ----------------
// 0x100000: G    u64[N*8]        (32KB)  gated selection bitmask (target-major)
// 0x108000: GT   u64[N*8]        (32KB)  transpose bitmask (built via atomicOr)
// 0x110000: idxl i32[N*KP]       (320KB) top-k source ids per target (ARBITRARY order)
// 0x160000: wgtl f32[N*KP]       (320KB) c^2 * rs_i  (row-scaled structural coeff)
// 0x1B0000: rs   f32[N]          1/sqrt(sum_k c_ik^2)   [max_common cancels]
// 0x1C0000: h    f32[BN*D]       (4MB)

union SMem {
    struct {                     // front blocks (~10KB)
        float cr[N];
        float q2[N];
        float ri[D];
        unsigned long long keys[N];
        unsigned hist[256];
        unsigned wc[8];
        unsigned vstar, above, cnt;
    } f;
    struct { float xs[16*64]; float Ws[64*64]; } g;   // GEMM blocks (20KB)
};

// blocks 0..511: cosine row + exact top-k SET for node i via radix-select.
//   Edge order is irrelevant downstream (all consumers are sums), so we select
//   the exact top-153 key set (distinct u64 keys: value<<9 | (511-j) tiebreak,
//   matching jax's smaller-index-wins) and compact in arbitrary order.
//   Radix-select: 8-bit digit histogram + wave-0 suffix scan; ~2-3 iters.
//   Replaces R7's O(N^2) rank scan (~2300 VALU inst + 256 LDS reads/thread).
// blocks 512..1535: h = x @ W rides the same dispatch (R7-proven form).
__global__ __launch_bounds__(256)
void k_front5(const float* __restrict__ emb, const float* __restrict__ x,
              const float* __restrict__ W, float* __restrict__ h,
              int* __restrict__ idxl, unsigned long long* __restrict__ G,
              unsigned long long* __restrict__ GT) {
    __shared__ SMem sm;
    int t = threadIdx.x;
    if (blockIdx.x >= 512) {                    // ---- h = x @ W ----
        int r0 = ((int)blockIdx.x - 512) * 16;
        ((float4*)sm.g.xs)[t] = ((const float4*)(x + r0*64))[t];
        for (int e = t; e < 1024; e += 256) ((float4*)sm.g.Ws)[e] = ((const float4*)W)[e];
        __syncthreads();
        int row = t >> 4, f0 = (t & 15)*4;
        float ax=0, ay=0, az=0, aw=0;
        #pragma unroll 8
        for (int c = 0; c < 64; ++c) {
            float xv = sm.g.xs[row*64+c];
            float4 wv = *(const float4*)&sm.g.Ws[c*64+f0];
            ax = fmaf(xv,wv.x,ax); ay = fmaf(xv,wv.y,ay);
            az = fmaf(xv,wv.z,az); aw = fmaf(xv,wv.w,aw);
        }
        float4 o; o.x=ax; o.y=ay; o.z=az; o.w=aw;
        ((float4*)(h + r0*64))[t] = o;
        return;
    }
    // ---- front: cosine row for node i ----
    int i = blockIdx.x;
    if (t < 16) ((float4*)sm.f.ri)[t] = ((const float4*)(emb + i*D))[t];
    __syncthreads();
    for (int j = t; j < N; j += 256) {          // dot(i,j), |j|^2 in one pass
        const float4* rj = (const float4*)(emb + j*D);
        float dot = 0.f, nsq = 0.f;
        #pragma unroll
        for (int q = 0; q < 16; ++q) {
            float4 v = rj[q];
            float4 u = ((const float4*)sm.f.ri)[q];             // LDS broadcast
            dot = fmaf(u.x,v.x,fmaf(u.y,v.y,fmaf(u.z,v.z,fmaf(u.w,v.w,dot))));
            nsq = fmaf(v.x,v.x,fmaf(v.y,v.y,fmaf(v.z,v.z,fmaf(v.w,v.w,nsq))));
        }
        sm.f.cr[j] = dot; sm.f.q2[j] = nsq;
    }
    __syncthreads();
    // sortable distinct keys: monotonic float->u32, index tiebreak (small j wins),
    // left-shifted so digit 7 holds the key MSBs.
    float ni = sqrtf(sm.f.q2[i]);
    for (int j = t; j < N; j += 256) {
        float c = sm.f.cr[j] / (ni*sqrtf(sm.f.q2[j]) + EPSF);
        unsigned u = __float_as_uint(c);
        unsigned s = (u >> 31) ? ~u : (u | 0x80000000u);
        sm.f.keys[j] = (((unsigned long long)s << 9) | (unsigned)(511 - j)) << 23;
    }
    __syncthreads();
    unsigned long long k0 = sm.f.keys[t], k1 = sm.f.keys[t+256];
    // ---- radix-select the 153rd-largest key ----
    unsigned need = TOPK;
    unsigned long long prefix = 0, prefmask = 0;
    for (int dig = 7; dig >= 0; --dig) {
        sm.f.hist[t] = 0;
        __syncthreads();
        int sh = dig*8;
        if ((k0 & prefmask) == prefix) atomicAdd(&sm.f.hist[(unsigned)(k0>>sh)&255], 1u);
        if ((k1 & prefmask) == prefix) atomicAdd(&sm.f.hist[(unsigned)(k1>>sh)&255], 1u);
        __syncthreads();
        if (t < 64) {                           // wave 0: suffix scan over 256 bins
            unsigned c0=sm.f.hist[4*t], c1=sm.f.hist[4*t+1],
                     c2=sm.f.hist[4*t+2], c3=sm.f.hist[4*t+3];
            unsigned T4 = c0+c1+c2+c3;
            unsigned S = T4;
            #pragma unroll
            for (int off = 1; off < 64; off <<= 1) {
                unsigned o = __shfl(S, (t+off < 64) ? t+off : t);
                S += (t+off < 64) ? o : 0;      // inclusive suffix sum of T4
            }
            unsigned a3 = S - T4;               // above(4t+3)
            unsigned a2 = a3+c3, a1 = a2+c2, a0 = a1+c1;
            if (a3 < need && need <= a3+c3) { sm.f.vstar=4*t+3; sm.f.above=a3; sm.f.cnt=c3; }
            if (a2 < need && need <= a2+c2) { sm.f.vstar=4*t+2; sm.f.above=a2; sm.f.cnt=c2; }
            if (a1 < need && need <= a1+c1) { sm.f.vstar=4*t+1; sm.f.above=a1; sm.f.cnt=c1; }
            if (a0 < need && need <= a0+c0) { sm.f.vstar=4*t;   sm.f.above=a0; sm.f.cnt=c0; }
        }
        __syncthreads();
        unsigned vs = sm.f.vstar, ab = sm.f.above, cv = sm.f.cnt;
        need -= ab;
        prefix  |= ((unsigned long long)vs) << sh;
        prefmask |= 0xFFull << sh;
        if (cv == need) break;                  // bin boundary exact -> done
    }
    // selection: exactly TOPK keys >= prefix (low bits of prefix are zero)
    bool s0 = (k0 >= prefix), s1 = (k1 >= prefix);
    unsigned long long b0 = __ballot(s0), b1 = __ballot(s1);
    int lane = t & 63, w = t >> 6;
    if (lane == 0) { sm.f.wc[w] = __popcll(b0); sm.f.wc[4+w] = __popcll(b1); }
    __syncthreads();
    unsigned base0 = 0, base1 = 0;
    #pragma unroll
    for (int m = 0; m < 8; ++m) {               // tiny serial prefix over 8 counts
        unsigned c = sm.f.wc[m];
        base0 += (m < w) ? c : 0;
        base1 += (m < 4+w) ? c : 0;
    }
    unsigned long long lml = (1ull << lane) - 1;
    if (s0) {
        idxl[i*KP + base0 + __popcll(b0 & lml)] = t;
        atomicOr(&GT[t*8 + (i>>6)], 1ull << (i&63));
    }
    if (s1) {
        idxl[i*KP + base1 + __popcll(b1 & lml)] = t + 256;
        atomicOr(&GT[(t+256)*8 + (i>>6)], 1ull << (i&63));
    }
    if (lane == 0) {                            // G row via ballot
        G[i*8 + w]     = b0;
        G[i*8 + 4 + w] = b1;
    }
}

// Per-edge popcount weights; nb rows built on the fly as G|GT|self
// (all L1/L2-resident, 32KB each). Stores c^2*rs_i; rs_i = 1/sqrt(sum c^2).
__global__ __launch_bounds__(256)
void k_edge2(const unsigned long long* __restrict__ G,
             const unsigned long long* __restrict__ GT,
             const int* __restrict__ idxl,
             float* __restrict__ wgtl, float* __restrict__ rs) {
    __shared__ unsigned long long ni[8];
    __shared__ float red[4];
    __shared__ float rsb;
    int i = blockIdx.x, k = threadIdx.x;
    if (k < 8) {
        unsigned long long v = G[i*8+k] | GT[i*8+k];
        if ((i>>6) == k) v |= 1ull << (i&63);    // self loop
        ni[k] = v;
    }
    __syncthreads();
    float c2 = 0.f;
    if (k < TOPK) {
        int j = idxl[i*KP+k];
        int jw = j >> 6; unsigned long long jb = 1ull << (j&63);
        int c = 0;
        #pragma unroll
        for (int w = 0; w < 8; ++w) {
            unsigned long long nj = G[j*8+w] | GT[j*8+w];
            if (w == jw) nj |= jb;               // self loop (compile-time w)
            c += __popcll(ni[w] & nj);
        }
        c2 = (float)(c*c);                       // edge always has c>=2
    }
    float s = c2;
    #pragma unroll
    for (int o = 32; o > 0; o >>= 1) s += __shfl_down(s, o, 64);
    if ((k & 63) == 0) red[k>>6] = s;
    __syncthreads();
    if (k == 0) {
        float deg = red[0]+red[1]+red[2]+red[3]; // > 0 always
        float r = (float)(1.0/sqrt((double)deg));
        rsb = r; rs[i] = r;
    }
    __syncthreads();
    if (k < TOPK) wgtl[i*KP+k] = c2 * rsb;
}

// h[b] staged in LDS (conflict-free b128 gather); indices/weights read from
// global (wave-broadcast, L2-hot); final weight = wn[k] * rs[j] on the fly.
__global__ __launch_bounds__(512)
void k_agg3(const float* __restrict__ h, const int* __restrict__ idxl,
            const float* __restrict__ wn, const float* __restrict__ rs,
            const float* __restrict__ bias, float* __restrict__ out) {
    __shared__ float4 hs4[512*16];   // 128KB: h[b] staged
    int chunk = blockIdx.x, b = blockIdx.y, t = threadIdx.x;
    const float4* hb = (const float4*)h + b*8192;
    for (int e = t; e < 8192; e += 512) hs4[e] = hb[e];
    int lane = t & 63, wv = t >> 6;
    int ts = lane >> 4, fq = lane & 15;
    int tl = wv*4 + ts;              // local target 0..31
    float4 bv = ((const float4*)bias)[fq];
    __syncthreads();
    #pragma unroll
    for (int grp = 0; grp < 2; ++grp) {
        int ti = chunk*64 + grp*32 + tl;
        const int*   ip = &idxl[ti*KP];
        const float* wp = &wn[ti*KP];
        float ax=0, ay=0, az=0, aw=0;
        #pragma unroll 4
        for (int kk = 0; kk < TOPK; ++kk) {
            int j = ip[kk];
            float w = wp[kk] * rs[j];
            float4 hv = hs4[j*16 + fq];
            ax = fmaf(w,hv.x,ax); ay = fmaf(w,hv.y,ay);
            az = fmaf(w,hv.z,az); aw = fmaf(w,hv.w,aw);
        }
        float4 o; o.x = ax+bv.x; o.y = ay+bv.y; o.z = az+bv.z; o.w = aw+bv.w;
        ((float4*)out)[(b*512 + ti)*16 + fq] = o;
    }
}

extern "C" void kernel_launch(void* const* d_in, const int* in_sizes, int n_in,
                              void* d_out, int out_size, void* d_ws, size_t ws_size,
                              hipStream_t stream) {
    const float* x    = (const float*)d_in[0];   // [32,512,64]
    const float* W    = (const float*)d_in[1];   // [64,64]
    const float* bias = (const float*)d_in[2];   // [64]
    const float* emb  = (const float*)d_in[3];   // [512,64]
    float* out = (float*)d_out;

    char* ws = (char*)d_ws;
    unsigned long long* G  = (unsigned long long*)(ws + 0x100000);
    unsigned long long* GT = (unsigned long long*)(ws + 0x108000);
    int*   idxl = (int*)(ws + 0x110000);
    float* wgtl = (float*)(ws + 0x160000);
    float* rs   = (float*)(ws + 0x1B0000);
    float* h    = (float*)(ws + 0x1C0000);

    hipMemsetAsync(GT, 0, N*8*sizeof(unsigned long long), stream);
    k_front5<<<512 + BN/16, 256, 0, stream>>>(emb, x, W, h, idxl, G, GT);
    k_edge2<<<N, 256, 0, stream>>>(G, GT, idxl, wgtl, rs);
    k_agg3<<<dim3(8, NB), 512, 0, stream>>>(h, idxl, wgtl, rs, bias, out);
}

// Round 10
// 50.183 us; speedup vs baseline: 1.6578x; 1.4529x over previous
//
#include <hip/hip_runtime.h>

#define N 512
#define TOPK 153
#define KP 160
#define D 64
#define NB 32          // batches
#define BN (NB*N)
#define EPSF 1e-8f

typedef __attribute__((ext_vector_type(8))) short bf16x8;   // 8 bf16 (4 VGPR)
typedef __attribute__((ext_vector_type(4))) float f32x4;

// byte-level XOR swizzle: spreads [f][1024B] rows across banks (T2)
#define SWZB(f, byte) ((byte) ^ (((f)&7)<<4))

static __device__ __forceinline__ unsigned bf16r(float v) {   // f32->bf16 RNE bits
    unsigned u = __float_as_uint(v);
    return (u + 0x7FFFu + ((u >> 16) & 1u)) >> 16;
}

// ---------------- ws layout (bytes) ----------------
// 0x100000: G    u64[N*8]    (32KB)   gated selection bitmask (target-major)
// 0x108000: GT   u64[N*8]    (32KB)   transpose bitmask (atomicOr)
// 0x110000: idxl i32[N*KP]   (320KB)  top-k source ids (arbitrary order)
// 0x160000: rs   f32[N]      1/sqrt(sum_k c_ik^2)  [max_common cancels]
// 0x170000: A_hi bf16[N*N]   (512KB)  dense c^2*rs_i, hi part
// 0x1F0000: A_lo bf16[N*N]   (512KB)  lo part (split precision)
// 0x280000: hT   f32[NB][64][N] (4MB) h transposed per batch

union SMem {
    struct {                     // front blocks (~10KB)
        float cr[N];
        float q2[N];
        float ri[D];
        unsigned long long keys[N];
        unsigned hist[256];
        unsigned vstar, above, cnt;
    } f;
    struct { float xs[16*64]; float Ws[64*64]; } g;   // GEMM blocks (20KB)
};

// blocks 0..511: cosine row + exact top-k SET via radix-select (R9-proven).
// blocks 512..1535: h = x @ W, written TRANSPOSED as hT[b][f][j] (float4
//   stores via (f, j-quad) thread mapping) for agg4's coalesced staging.
__global__ __launch_bounds__(256)
void k_front6(const float* __restrict__ emb, const float* __restrict__ x,
              const float* __restrict__ W, float* __restrict__ hT,
              int* __restrict__ idxl, unsigned long long* __restrict__ G,
              unsigned long long* __restrict__ GT) {
    __shared__ SMem sm;
    int t = threadIdx.x;
    if (blockIdx.x >= 512) {                    // ---- h = x @ W -> hT ----
        int blk = (int)blockIdx.x - 512;        // 0..1023
        int r0 = blk * 16;                      // global row base
        int b  = r0 >> 9, jb = r0 & 511;
        ((float4*)sm.g.xs)[t] = ((const float4*)(x + r0*64))[t];
        for (int e = t; e < 1024; e += 256) ((float4*)sm.g.Ws)[e] = ((const float4*)W)[e];
        __syncthreads();
        int f = t & 63, jq = t >> 6;            // feature, j-quad (0..3)
        float a0=0,a1=0,a2=0,a3=0;
        #pragma unroll
        for (int c = 0; c < 64; c += 4) {
            float4 x0 = *(const float4*)&sm.g.xs[(jq*4+0)*64 + c];   // broadcast
            float4 x1 = *(const float4*)&sm.g.xs[(jq*4+1)*64 + c];
            float4 x2 = *(const float4*)&sm.g.xs[(jq*4+2)*64 + c];
            float4 x3 = *(const float4*)&sm.g.xs[(jq*4+3)*64 + c];
            float w0 = sm.g.Ws[c*64+f],     w1 = sm.g.Ws[(c+1)*64+f];
            float w2 = sm.g.Ws[(c+2)*64+f], w3 = sm.g.Ws[(c+3)*64+f];
            a0 = fmaf(x0.x,w0,fmaf(x0.y,w1,fmaf(x0.z,w2,fmaf(x0.w,w3,a0))));
            a1 = fmaf(x1.x,w0,fmaf(x1.y,w1,fmaf(x1.z,w2,fmaf(x1.w,w3,a1))));
            a2 = fmaf(x2.x,w0,fmaf(x2.y,w1,fmaf(x2.z,w2,fmaf(x2.w,w3,a2))));
            a3 = fmaf(x3.x,w0,fmaf(x3.y,w1,fmaf(x3.z,w2,fmaf(x3.w,w3,a3))));
        }
        float4 o; o.x=a0; o.y=a1; o.z=a2; o.w=a3;    // 4 consecutive j, fixed f
        *(float4*)&hT[((size_t)b*64 + f)*512 + jb + jq*4] = o;
        return;
    }
    // ---- front: cosine row for node i ----
    int i = blockIdx.x;
    if (t < 16) ((float4*)sm.f.ri)[t] = ((const float4*)(emb + i*D))[t];
    __syncthreads();
    for (int j = t; j < N; j += 256) {
        const float4* rj = (const float4*)(emb + j*D);
        float dot = 0.f, nsq = 0.f;
        #pragma unroll
        for (int q = 0; q < 16; ++q) {
            float4 v = rj[q];
            float4 u = ((const float4*)sm.f.ri)[q];
            dot = fmaf(u.x,v.x,fmaf(u.y,v.y,fmaf(u.z,v.z,fmaf(u.w,v.w,dot))));
            nsq = fmaf(v.x,v.x,fmaf(v.y,v.y,fmaf(v.z,v.z,fmaf(v.w,v.w,nsq))));
        }
        sm.f.cr[j] = dot; sm.f.q2[j] = nsq;
    }
    __syncthreads();
    float ni = sqrtf(sm.f.q2[i]);
    for (int j = t; j < N; j += 256) {
        float c = sm.f.cr[j] / (ni*sqrtf(sm.f.q2[j]) + EPSF);
        unsigned u = __float_as_uint(c);
        unsigned s = (u >> 31) ? ~u : (u | 0x80000000u);
        sm.f.keys[j] = (((unsigned long long)s << 9) | (unsigned)(511 - j)) << 23;
    }
    __syncthreads();
    unsigned long long k0 = sm.f.keys[t], k1 = sm.f.keys[t+256];
    unsigned need = TOPK;
    unsigned long long prefix = 0, prefmask = 0;
    for (int dig = 7; dig >= 0; --dig) {
        sm.f.hist[t] = 0;
        __syncthreads();
        int sh = dig*8;
        if ((k0 & prefmask) == prefix) atomicAdd(&sm.f.hist[(unsigned)(k0>>sh)&255], 1u);
        if ((k1 & prefmask) == prefix) atomicAdd(&sm.f.hist[(unsigned)(k1>>sh)&255], 1u);
        __syncthreads();
        if (t < 64) {
            unsigned c0=sm.f.hist[4*t], c1=sm.f.hist[4*t+1],
                     c2=sm.f.hist[4*t+2], c3=sm.f.hist[4*t+3];
            unsigned T4 = c0+c1+c2+c3;
            unsigned S = T4;
            #pragma unroll
            for (int off = 1; off < 64; off <<= 1) {
                unsigned o = __shfl(S, (t+off < 64) ? t+off : t);
                S += (t+off < 64) ? o : 0;
            }
            unsigned a3 = S - T4;
            unsigned a2 = a3+c3, a1 = a2+c2, a0 = a1+c1;
            if (a3 < need && need <= a3+c3) { sm.f.vstar=4*t+3; sm.f.above=a3; sm.f.cnt=c3; }
            if (a2 < need && need <= a2+c2) { sm.f.vstar=4*t+2; sm.f.above=a2; sm.f.cnt=c2; }
            if (a1 < need && need <= a1+c1) { sm.f.vstar=4*t+1; sm.f.above=a1; sm.f.cnt=c1; }
            if (a0 < need && need <= a0+c0) { sm.f.vstar=4*t;   sm.f.above=a0; sm.f.cnt=c0; }
        }
        __syncthreads();
        unsigned vs = sm.f.vstar, ab = sm.f.above, cv = sm.f.cnt;
        need -= ab;
        prefix   |= ((unsigned long long)vs) << sh;
        prefmask |= 0xFFull << sh;
        if (cv == need) break;
    }
    bool s0 = (k0 >= prefix), s1 = (k1 >= prefix);
    unsigned long long b0 = __ballot(s0), b1 = __ballot(s1);
    int lane = t & 63, w = t >> 6;
    // compact within wave (order within idxl irrelevant downstream)
    unsigned long long lml = (1ull << lane) - 1;
    __shared__ unsigned wc_[8];
    if (lane == 0) { wc_[w] = __popcll(b0); wc_[4+w] = __popcll(b1); }
    __syncthreads();
    unsigned base0 = 0, base1 = 0;
    #pragma unroll
    for (int m = 0; m < 8; ++m) {
        unsigned c = wc_[m];
        base0 += (m < w) ? c : 0;
        base1 += (m < 4+w) ? c : 0;
    }
    if (s0) {
        idxl[i*KP + base0 + __popcll(b0 & lml)] = t;
        atomicOr(&GT[t*8 + (i>>6)], 1ull << (i&63));
    }
    if (s1) {
        idxl[i*KP + base1 + __popcll(b1 & lml)] = t + 256;
        atomicOr(&GT[(t+256)*8 + (i>>6)], 1ull << (i&63));
    }
    if (lane == 0) { G[i*8 + w] = b0; G[i*8 + 4 + w] = b1; }
}

// Per-edge popcount weights -> DENSE A row i in bf16 hi/lo (zero + scatter).
// A[i][j] = c^2 * rs_i  (rs_j folded into the B operand during agg staging).
__global__ __launch_bounds__(256)
void k_edge3(const unsigned long long* __restrict__ G,
             const unsigned long long* __restrict__ GT,
             const int* __restrict__ idxl, float* __restrict__ rs,
             unsigned short* __restrict__ A_hi, unsigned short* __restrict__ A_lo) {
    __shared__ unsigned long long ni[8];
    __shared__ float red[4];
    __shared__ float rsb;
    int i = blockIdx.x, k = threadIdx.x;
    if (k < 8) {
        unsigned long long v = G[i*8+k] | GT[i*8+k];
        if ((i>>6) == k) v |= 1ull << (i&63);
        ni[k] = v;
    }
    ((unsigned*)(A_hi + (size_t)i*512))[k] = 0;   // zero row (256 u32 = 512 bf16)
    ((unsigned*)(A_lo + (size_t)i*512))[k] = 0;
    __syncthreads();
    float c2 = 0.f; int j = 0;
    if (k < TOPK) {
        j = idxl[i*KP+k];
        int jw = j >> 6; unsigned long long jb = 1ull << (j&63);
        int c = 0;
        #pragma unroll
        for (int w = 0; w < 8; ++w) {
            unsigned long long nj = G[j*8+w] | GT[j*8+w];
            if (w == jw) nj |= jb;
            c += __popcll(ni[w] & nj);
        }
        c2 = (float)(c*c);
    }
    float s = c2;
    #pragma unroll
    for (int o = 32; o > 0; o >>= 1) s += __shfl_down(s, o, 64);
    if ((k & 63) == 0) red[k>>6] = s;
    __syncthreads();
    if (k == 0) {
        float deg = red[0]+red[1]+red[2]+red[3];
        float r = (float)(1.0/sqrt((double)deg));
        rsb = r; rs[i] = r;
    }
    __syncthreads();
    if (k < TOPK) {
        float wv = c2 * rsb;
        unsigned hb = bf16r(wv);
        float fhi = __uint_as_float(hb << 16);
        unsigned lb = bf16r(wv - fhi);
        A_hi[(size_t)i*512 + j] = (unsigned short)hb;
        A_lo[(size_t)i*512 + j] = (unsigned short)lb;
    }
}

// Dense MFMA aggregate: out_b = A @ (rs .* h_b) + bias, bf16-split 3-pass.
// LDS: g[f][j] bf16 hi/lo, XOR-swizzled (T2). A frags straight from global
// (L2-hot, 16B/lane, A row = lane&15, k-octet = lane>>4). C: col=lane&15,
// row=(lane>>4)*4+reg (m89). Block = 64 targets x 64 feats x one batch.
__global__ __launch_bounds__(512)
void k_agg4(const float* __restrict__ hT, const float* __restrict__ rs,
            const unsigned short* __restrict__ Ahg, const unsigned short* __restrict__ Alg,
            const float* __restrict__ bias, float* __restrict__ out) {
    __shared__ char glds[131072];        // [0,64K): g_hi   [64K,128K): g_lo
    int chunk = blockIdx.x, b = blockIdx.y, t = threadIdx.x;
    const float4* hb = (const float4*)(hT + (size_t)b*64*512);
    for (int e = t; e < 8192; e += 512) {
        int f = e >> 7;
        int j0 = (e & 127) << 2;
        float4 v = hb[e];
        float4 rv = *(const float4*)&rs[j0];
        float v0 = v.x*rv.x, v1 = v.y*rv.y, v2 = v.z*rv.z, v3 = v.w*rv.w;
        unsigned h0 = bf16r(v0), h1 = bf16r(v1), h2 = bf16r(v2), h3 = bf16r(v3);
        unsigned l0 = bf16r(v0 - __uint_as_float(h0<<16));
        unsigned l1 = bf16r(v1 - __uint_as_float(h1<<16));
        unsigned l2 = bf16r(v2 - __uint_as_float(h2<<16));
        unsigned l3 = bf16r(v3 - __uint_as_float(h3<<16));
        unsigned long long hp = (unsigned long long)h0 | ((unsigned long long)h1<<16)
                              | ((unsigned long long)h2<<32) | ((unsigned long long)h3<<48);
        unsigned long long lp = (unsigned long long)l0 | ((unsigned long long)l1<<16)
                              | ((unsigned long long)l2<<32) | ((unsigned long long)l3<<48);
        int byte = f*1024 + j0*2;
        *(unsigned long long*)(glds + SWZB(f, byte)) = hp;
        *(unsigned long long*)(glds + 65536 + SWZB(f, byte)) = lp;
    }
    __syncthreads();
    int wid = t >> 6, l = t & 63;
    int wr = wid >> 1, wc = wid & 1;
    int m = l & 15, kg = (l >> 4) * 8;
    int trow = chunk*64 + wr*16 + m;
    const unsigned short* arh = Ahg + (size_t)trow*512 + kg;
    const unsigned short* arl = Alg + (size_t)trow*512 + kg;
    int f0 = wc*32 + m, f1 = f0 + 16;
    f32x4 acc0 = {0.f,0.f,0.f,0.f}, acc1 = {0.f,0.f,0.f,0.f};
    #pragma unroll 4
    for (int k0 = 0; k0 < 512; k0 += 32) {
        bf16x8 Ah = *(const bf16x8*)(arh + k0);
        bf16x8 Al = *(const bf16x8*)(arl + k0);
        int kb = (k0 + kg) * 2;
        bf16x8 B0h = *(const bf16x8*)(glds + SWZB(f0, f0*1024 + kb));
        bf16x8 B0l = *(const bf16x8*)(glds + 65536 + SWZB(f0, f0*1024 + kb));
        bf16x8 B1h = *(const bf16x8*)(glds + SWZB(f1, f1*1024 + kb));
        bf16x8 B1l = *(const bf16x8*)(glds + 65536 + SWZB(f1, f1*1024 + kb));
        acc0 = __builtin_amdgcn_mfma_f32_16x16x32_bf16(Ah, B0h, acc0, 0, 0, 0);
        acc0 = __builtin_amdgcn_mfma_f32_16x16x32_bf16(Ah, B0l, acc0, 0, 0, 0);
        acc0 = __builtin_amdgcn_mfma_f32_16x16x32_bf16(Al, B0h, acc0, 0, 0, 0);
        acc1 = __builtin_amdgcn_mfma_f32_16x16x32_bf16(Ah, B1h, acc1, 0, 0, 0);
        acc1 = __builtin_amdgcn_mfma_f32_16x16x32_bf16(Ah, B1l, acc1, 0, 0, 0);
        acc1 = __builtin_amdgcn_mfma_f32_16x16x32_bf16(Al, B1h, acc1, 0, 0, 0);
    }
    float bb0 = bias[f0], bb1 = bias[f1];
    size_t ob = (size_t)(b*512 + chunk*64 + wr*16) * 64;
    #pragma unroll
    for (int r = 0; r < 4; ++r) {
        int row = (l >> 4) * 4 + r;
        out[ob + (size_t)row*64 + f0] = acc0[r] + bb0;
        out[ob + (size_t)row*64 + f1] = acc1[r] + bb1;
    }
}

extern "C" void kernel_launch(void* const* d_in, const int* in_sizes, int n_in,
                              void* d_out, int out_size, void* d_ws, size_t ws_size,
                              hipStream_t stream) {
    const float* x    = (const float*)d_in[0];   // [32,512,64]
    const float* W    = (const float*)d_in[1];   // [64,64]
    const float* bias = (const float*)d_in[2];   // [64]
    const float* emb  = (const float*)d_in[3];   // [512,64]
    float* out = (float*)d_out;

    char* ws = (char*)d_ws;
    unsigned long long* G  = (unsigned long long*)(ws + 0x100000);
    unsigned long long* GT = (unsigned long long*)(ws + 0x108000);
    int*   idxl = (int*)(ws + 0x110000);
    float* rs   = (float*)(ws + 0x160000);
    unsigned short* A_hi = (unsigned short*)(ws + 0x170000);
    unsigned short* A_lo = (unsigned short*)(ws + 0x1F0000);
    float* hT   = (float*)(ws + 0x280000);

    hipMemsetAsync(GT, 0, N*8*sizeof(unsigned long long), stream);
    k_front6<<<512 + BN/16, 256, 0, stream>>>(emb, x, W, hT, idxl, G, GT);
    k_edge3<<<N, 256, 0, stream>>>(G, GT, idxl, rs, A_hi, A_lo);
    k_agg4<<<dim3(8, NB), 512, 0, stream>>>(hT, rs, A_hi, A_lo, bias, out);
}